// Round 10
// baseline (224.596 us; speedup 1.0000x reference)
//
#include <hip/hip_runtime.h>
#include <math.h>

#define NTH 256
#define NTH2 512
#define NTH3 512
#define LSEQ 2048
#define NF 4096
#define NH 512
#define NS 64
#define NB 8
#define NPAIR 256
#define TWO_PI 6.2831853071795864769f
// XOR swizzle: bijective, modifies only bits 0-3; spreads every FFT pass's
// lane pattern evenly over banks.
#define SW(i) ((i) ^ (((i) >> 4) & 15) ^ (((i) >> 8) & 15))
#define DR11(l) ((((l) & 15) << 7) | ((((l) >> 4) & 15) << 3) | ((l) >> 8))

#define C16_1 0.9238795325112867f
#define C16_2 0.7071067811865476f
#define C16_3 0.3826834323650898f

__device__ __forceinline__ float frcp(float x) {
    return __builtin_amdgcn_rcpf(x);
}

__device__ __forceinline__ float2 cmul(float2 a, float2 b) {
    return make_float2(a.x*b.x - a.y*b.y, a.x*b.y + a.y*b.x);
}
__device__ __forceinline__ float2 cmulw(float2 a, float wr, float wi) {
    return make_float2(a.x*wr - a.y*wi, a.x*wi + a.y*wr);
}

// ---- stages 2..4 of the 16-point DIF DFT (shared tail) ----
template<bool INV>
__device__ __forceinline__ void fft16_tail(float2* y) {
    const float sg = INV ? -1.f : 1.f;
    const float WR[8] = {1.f, C16_1, C16_2, C16_3, 0.f, -C16_3, -C16_2, -C16_1};
    const float WI[8] = {0.f, -C16_3, -C16_2, -C16_1, -1.f, -C16_1, -C16_2, -C16_3};
    #pragma unroll
    for (int h = 0; h < 16; h += 8)
        #pragma unroll
        for (int j = 0; j < 4; ++j) {
            float2 a = y[h+j], b = y[h+j+4];
            float2 d = make_float2(a.x-b.x, a.y-b.y);
            y[h+j] = make_float2(a.x+b.x, a.y+b.y);
            y[h+j+4] = cmulw(d, WR[2*j], sg*WI[2*j]);
        }
    #pragma unroll
    for (int h = 0; h < 16; h += 4)
        #pragma unroll
        for (int j = 0; j < 2; ++j) {
            float2 a = y[h+j], b = y[h+j+2];
            float2 d = make_float2(a.x-b.x, a.y-b.y);
            y[h+j] = make_float2(a.x+b.x, a.y+b.y);
            y[h+j+2] = (j == 0) ? d : make_float2(sg*d.y, -sg*d.x);
        }
    #pragma unroll
    for (int h = 0; h < 16; h += 2) {
        float2 a = y[h], b = y[h+1];
        y[h] = make_float2(a.x+b.x, a.y+b.y);
        y[h+1] = make_float2(a.x-b.x, a.y-b.y);
    }
}

// ---- full 16-point DIF DFT. Output: Y[k] = y[rev4[k]]. ----
template<bool INV>
__device__ __forceinline__ void fft16(float2* y) {
    const float sg = INV ? -1.f : 1.f;
    const float WR[8] = {1.f, C16_1, C16_2, C16_3, 0.f, -C16_3, -C16_2, -C16_1};
    const float WI[8] = {0.f, -C16_3, -C16_2, -C16_1, -1.f, -C16_1, -C16_2, -C16_3};
    #pragma unroll
    for (int j = 0; j < 8; ++j) {
        float2 a = y[j], b = y[j+8];
        float2 d = make_float2(a.x-b.x, a.y-b.y);
        y[j] = make_float2(a.x+b.x, a.y+b.y);
        y[j+8] = cmulw(d, WR[j], sg*WI[j]);
    }
    fft16_tail<INV>(y);
}

// ---- 8-point DIF DFT. Output: Y[k] = y[rev3[k]]. ----
template<bool INV>
__device__ __forceinline__ void fft8(float2* y) {
    const float sg = INV ? -1.f : 1.f;
    const float WR[4] = {1.f, C16_2, 0.f, -C16_2};
    const float WI[4] = {0.f, -C16_2, -1.f, -C16_2};
    #pragma unroll
    for (int j = 0; j < 4; ++j) {
        float2 a = y[j], b = y[j+4];
        float2 d = make_float2(a.x-b.x, a.y-b.y);
        y[j] = make_float2(a.x+b.x, a.y+b.y);
        y[j+4] = cmulw(d, WR[j], sg*WI[j]);
    }
    #pragma unroll
    for (int h = 0; h < 8; h += 4)
        #pragma unroll
        for (int j = 0; j < 2; ++j) {
            float2 a = y[h+j], b = y[h+j+2];
            float2 d = make_float2(a.x-b.x, a.y-b.y);
            y[h+j] = make_float2(a.x+b.x, a.y+b.y);
            y[h+j+2] = (j == 0) ? d : make_float2(sg*d.y, -sg*d.x);
        }
    #pragma unroll
    for (int h = 0; h < 8; h += 2) {
        float2 a = y[h], b = y[h+1];
        y[h] = make_float2(a.x+b.x, a.y+b.y);
        y[h+1] = make_float2(a.x-b.x, a.y-b.y);
    }
}

// Radix-16 pass on swizzled LDS. INV=false: DIF forward (natural->DR).
// INV=true: DIT inverse (DR->natural). NOTW=true: all twiddles are 1.
template<bool INV, bool NOTW = false>
__device__ __forceinline__ void pass16(float2* s, int base, int str, float ang1) {
    const int rev4[16] = {0,8,4,12,2,10,6,14,1,9,5,13,3,11,7,15};
    float2 y[16];
    if (!INV) {
        #pragma unroll
        for (int j = 0; j < 16; ++j) y[j] = s[SW(base + j*str)];
        fft16<false>(y);
        if (NOTW) {
            #pragma unroll
            for (int k = 0; k < 16; ++k) s[SW(base + k*str)] = y[rev4[k]];
        } else {
            float sn, cs;
            __sincosf(ang1, &sn, &cs);
            float2 wb = make_float2(cs, sn);
            float2 w = make_float2(1.f, 0.f);
            s[SW(base)] = y[0];
            #pragma unroll
            for (int k = 1; k < 16; ++k) {
                w = cmul(w, wb);
                s[SW(base + k*str)] = cmul(y[rev4[k]], w);
            }
        }
    } else {
        if (NOTW) {
            #pragma unroll
            for (int k = 0; k < 16; ++k) y[k] = s[SW(base + k*str)];
        } else {
            float sn, cs;
            __sincosf(ang1, &sn, &cs);
            float2 wb = make_float2(cs, sn);
            float2 w = make_float2(1.f, 0.f);
            y[0] = s[SW(base)];
            #pragma unroll
            for (int k = 1; k < 16; ++k) {
                w = cmul(w, wb);
                y[k] = cmul(s[SW(base + k*str)], w);
            }
        }
        fft16<true>(y);
        #pragma unroll
        for (int j = 0; j < 16; ++j) s[SW(base + j*str)] = y[rev4[j]];
    }
}

// Forward radix-16 pass with implicit-zero top half (j>=8 inputs are zero).
__device__ __forceinline__ void pass16_z(float2* s, int base, int str, float ang1) {
    const int rev4[16] = {0,8,4,12,2,10,6,14,1,9,5,13,3,11,7,15};
    const float WR[8] = {1.f, C16_1, C16_2, C16_3, 0.f, -C16_3, -C16_2, -C16_1};
    const float WI[8] = {0.f, -C16_3, -C16_2, -C16_1, -1.f, -C16_1, -C16_2, -C16_3};
    float2 y[16];
    float sn, cs;
    __sincosf(ang1, &sn, &cs);
    float2 wb = make_float2(cs, sn);
    #pragma unroll
    for (int j = 0; j < 8; ++j) y[j] = s[SW(base + j*str)];
    #pragma unroll
    for (int j = 0; j < 8; ++j) y[j+8] = cmulw(y[j], WR[j], WI[j]);
    fft16_tail<false>(y);
    float2 w = make_float2(1.f, 0.f);
    s[SW(base)] = y[0];
    #pragma unroll
    for (int k = 1; k < 16; ++k) {
        w = cmul(w, wb);
        s[SW(base + k*str)] = cmul(y[rev4[k]], w);
    }
}

// Final inverse radix-16 pass: only j<8 outputs (t<2048) are needed.
__device__ __forceinline__ void pass16_li(float2* s, int base, int str, float ang1) {
    const int rev4[16] = {0,8,4,12,2,10,6,14,1,9,5,13,3,11,7,15};
    float2 y[16];
    float sn, cs;
    __sincosf(ang1, &sn, &cs);
    float2 wb = make_float2(cs, sn);
    float2 w = make_float2(1.f, 0.f);
    y[0] = s[SW(base)];
    #pragma unroll
    for (int k = 1; k < 16; ++k) {
        w = cmul(w, wb);
        y[k] = cmul(s[SW(base + k*str)], w);
    }
    fft16<true>(y);
    #pragma unroll
    for (int j = 0; j < 8; ++j) s[SW(base + j*str)] = y[rev4[j]];
}

template<bool INV, bool NOTW = false>
__device__ __forceinline__ void pass8(float2* s, int base, int str, float ang1) {
    const int rev3[8] = {0,4,2,6,1,5,3,7};
    float2 y[8];
    if (!INV) {
        #pragma unroll
        for (int j = 0; j < 8; ++j) y[j] = s[SW(base + j*str)];
        fft8<false>(y);
        if (NOTW) {
            #pragma unroll
            for (int k = 0; k < 8; ++k) s[SW(base + k*str)] = y[rev3[k]];
        } else {
            float sn, cs;
            __sincosf(ang1, &sn, &cs);
            float2 wb = make_float2(cs, sn);
            float2 w = make_float2(1.f, 0.f);
            s[SW(base)] = y[0];
            #pragma unroll
            for (int k = 1; k < 8; ++k) {
                w = cmul(w, wb);
                s[SW(base + k*str)] = cmul(y[rev3[k]], w);
            }
        }
    } else {
        if (NOTW) {
            #pragma unroll
            for (int k = 0; k < 8; ++k) y[k] = s[SW(base + k*str)];
        } else {
            float sn, cs;
            __sincosf(ang1, &sn, &cs);
            float2 wb = make_float2(cs, sn);
            float2 w = make_float2(1.f, 0.f);
            y[0] = s[SW(base)];
            #pragma unroll
            for (int k = 1; k < 8; ++k) {
                w = cmul(w, wb);
                y[k] = cmul(s[SW(base + k*str)], w);
            }
        }
        fft8<true>(y);
        #pragma unroll
        for (int j = 0; j < 8; ++j) s[SW(base + j*str)] = y[rev3[j]];
    }
}

// Transpose u [b][t][hp]f2 -> W [hp][b][t]f2 via 64x64 LDS tiles.
__global__ __launch_bounds__(NTH) void k_tu(
    const float2* __restrict__ u2, float2* __restrict__ W)
{
    __shared__ float2 tile[64][65];
    const int t0 = blockIdx.x * 64, hp0 = blockIdx.y * 64, b = blockIdx.z;
    const int tx = threadIdx.x & 63, ty = threadIdx.x >> 6;
    #pragma unroll
    for (int r = 0; r < 64; r += 4)
        tile[r + ty][tx] = u2[((size_t)b * LSEQ + t0 + r + ty) * NPAIR + hp0 + tx];
    __syncthreads();
    #pragma unroll
    for (int r = 0; r < 64; r += 4)
        W[(((size_t)(hp0 + r + ty) * NB + b) << 11) + t0 + tx] = tile[tx][r + ty];
}

// Transpose W [hp][b][t]f2 -> out [b][t][hp]f2.
__global__ __launch_bounds__(NTH) void k_ty(
    const float2* __restrict__ W, float2* __restrict__ out2)
{
    __shared__ float2 tile[64][65];
    const int t0 = blockIdx.x * 64, hp0 = blockIdx.y * 64, b = blockIdx.z;
    const int tx = threadIdx.x & 63, ty = threadIdx.x >> 6;
    #pragma unroll
    for (int r = 0; r < 64; r += 4)   // tile[hp_local][t_local]
        tile[r + ty][tx] = W[(((size_t)(hp0 + r + ty) * NB + b) << 11) + t0 + tx];
    __syncthreads();
    #pragma unroll
    for (int r = 0; r < 64; r += 4)
        out2[((size_t)b * LSEQ + t0 + r + ty) * NPAIR + hp0 + tx] = tile[tx][r + ty];
}

// MERGED k_cauchy + k_kspec, 512-THREAD blocks (8 waves): the Cauchy phase
// uses all 512 threads (4 freqs each, lane-stride-1 assignment l = u+256j)
// giving 16 waves/CU during the VALU-heavy phase -- round-9's 256-thread
// version was grid-starved at 8 waves/CU (Occupancy 15%, VALU 63%).
// Mirror handoff via transposed staging sM[j*256+u]: stride-1 writes and
// reads, zero bank conflicts (round-9's Lx[8t+j] layout conflicted 4-8x).
// Lo threads combine A in registers, then fill sA + DR-ordered sW; the
// kspec FFT pipeline (verbatim) runs with its original 128/256-thread
// shapes; bin-write loops flattened to 512-thread stride. LDS ~35 KB.
__global__ __launch_bounds__(NTH3, 2) void k_ck(
    const float* __restrict__ Lre, const float* __restrict__ Lim,
    const float* __restrict__ Pm, const float* __restrict__ Bm,
    const float* __restrict__ Cm, const float* __restrict__ logstep,
    const float* __restrict__ Dp, float2* __restrict__ KfP)
{
    __shared__ float2 sW[LSEQ];        // 16 KB
    __shared__ float2 sA[1040];        // 8.3 KB: A[0..1024] at sA[l+(l>>7)]
    __shared__ float2 sM[1024];        // 8 KB: mirror staging, sM[j*256+u]
    __shared__ float4 cA[NS];          // dre, dre^2, lam_im, |P|^2
    __shared__ float4 cB[NS];          // conj(C)B, conj(C)P
    __shared__ float2 cC[NS];          // conj(P)B
    const int h = blockIdx.x;
    const int tid = threadIdx.x;
    if (tid < NS) {
        int i = h * NS + tid;
        float Lxx = fminf(Lre[i], -1e-4f), Lyy = Lim[i];
        float Px = Pm[2*i], Py = Pm[2*i+1];
        float Bx = Bm[2*i], By = Bm[2*i+1];
        float Cx = Cm[2*i], Cy = Cm[2*i+1];
        float dre = -Lxx;
        cA[tid] = make_float4(dre, dre*dre, Lyy, Px*Px + Py*Py);
        cB[tid] = make_float4(Cx*Bx + Cy*By, Cx*By - Cy*Bx,
                              Cx*Px + Cy*Py, Cx*Py - Cy*Px);
        cC[tid] = make_float2(Px*Bx + Py*By, Px*By - Py*Bx);
    }
    __syncthreads();
    const float step = expf(logstep[h]);
    const float a2s = 2.0f / step;
    // ---- Cauchy: 4 freqs/thread, lane-stride-1 ----
    // lo (tid<256): l = u + 256*j, u = tid, covers 0..1023
    // hi (tid>=256): l = 2048 - (u + 256*j), u = tid-256, covers 1025..2048
    const int lo = (tid < 256);
    const int u = lo ? tid : (tid - 256);
    float tg[4], g1v[4];
    #pragma unroll
    for (int j = 0; j < 4; ++j) {
        int l = lo ? (u + 256 * j) : (LSEQ - (u + 256 * j));
        float r = (float)l * (1.0f / (float)LSEQ);
        tg[j] = sinpif(r) * frcp(cospif(r));     // tan(pi*l/L)
        g1v[j] = a2s * tg[j];
    }
    float a0[4] = {0,0,0,0}, a1[4] = {0,0,0,0};
    float a2[4] = {0,0,0,0}, a3[4] = {0,0,0,0};
    float a4[4] = {0,0,0,0}, a5[4] = {0,0,0,0};
    float a6[4] = {0,0,0,0}, a7[4] = {0,0,0,0};
    for (int n = 0; n < NS; ++n) {
        float4 ca = cA[n];
        float4 cb = cB[n];
        float2 cc = cC[n];
        #pragma unroll
        for (int j = 0; j < 4; ++j) {
            float di = g1v[j] - ca.z;
            float iv = frcp(fmaf(di, di, ca.y));
            float rx = ca.x * iv, ry = di * iv;  // rec = rx - i*ry
            a0[j] += cb.x*rx + cb.y*ry;  a1[j] += cb.y*rx - cb.x*ry;
            a2[j] += cb.z*rx + cb.w*ry;  a3[j] += cb.w*rx - cb.z*ry;
            a4[j] += cc.x*rx + cc.y*ry;  a5[j] += cc.y*rx - cc.x*ry;
            a6[j] += ca.w*rx;            a7[j] -= ca.w*ry;
        }
    }
    // finalize: (1 + i*tg) * (s00 - s01*s10/(1+s11)); keep in registers
    float arx[4], ary[4];
    #pragma unroll
    for (int j = 0; j < 4; ++j) {
        float denx = 1.0f + a6[j], deny = a7[j];
        float dinv = frcp(denx*denx + deny*deny);
        float numx = a2[j]*a4[j] - a3[j]*a5[j];
        float numy = a2[j]*a5[j] + a3[j]*a4[j];
        float qx = (numx*denx + numy*deny) * dinv;
        float qy = (numy*denx - numx*deny) * dinv;
        float kx = a0[j] - qx, ky = a1[j] - qy;
        arx[j] = kx - tg[j]*ky;
        ary[j] = ky + tg[j]*kx;
    }
    float amx = 0.f;
    if (tid == 0) {
        // l = 1024: tan -> inf limit, A[1024] = Re((step/2)*sum(conj(C)B))
        float sx = 0.f;
        for (int n = 0; n < NS; ++n) sx += cB[n].x;
        amx = 0.5f * step * sx;
    }
    if (!lo) {
        #pragma unroll
        for (int j = 0; j < 4; ++j)
            sM[j * 256 + u] = make_float2(arx[j], ary[j]);   // stride-1 lanes
    }
    __syncthreads();
    // ---- mirror-combine A; fill sA + DR-ordered sW (kspec input) ----
    if (lo) {
        #pragma unroll
        for (int j = 0; j < 4; ++j) {
            int l = u + 256 * j;
            float2 mz = sM[j * 256 + u];       // at[2048-l], stride-1 lanes
            float2 A = make_float2(0.5f*(arx[j] + mz.x), 0.5f*(ary[j] - mz.y));
            sA[l + (l >> 7)] = A;
            sW[SW(DR11(l))] = A;
            if (l > 0) sW[SW(DR11(LSEQ - l))] = make_float2(A.x, -A.y);
        }
    }
    if (tid == 0) {
        float2 Am = make_float2(amx, 0.f);
        sA[1024 + (1024 >> 7)] = Am;
        sW[SW(DR11(1024))] = Am;
    }
    __syncthreads();
    // inverse DIT-2048 (DR -> natural time)
    if (tid < 256) pass8<true, true>(sW, tid << 3, 1, 0.f);
    __syncthreads();
    if (tid < 128) pass16<true>(sW, ((tid >> 3) << 7) | (tid & 7), 8,
                                TWO_PI * (float)(tid & 7) / 128.f);
    __syncthreads();
    if (tid < 128) pass16<true>(sW, tid, 128, TWO_PI * (float)tid / 2048.f);
    __syncthreads();
    // modulate: K[t]/2048 * e^{-2pi i t/4096}
    for (int t = tid; t < LSEQ; t += NTH3) {
        float kv = sW[SW(t)].x * (1.0f / (float)LSEQ);
        float sn, cs;
        __sincosf(-TWO_PI * (float)t / (float)NF, &sn, &cs);
        sW[SW(t)] = make_float2(kv * cs, kv * sn);
    }
    __syncthreads();
    // forward DIF-2048 (natural -> DR spectrum)
    if (tid < 128) pass16<false>(sW, tid, 128, -TWO_PI * (float)tid / 2048.f);
    __syncthreads();
    if (tid < 128) pass16<false>(sW, ((tid >> 3) << 7) | (tid & 7), 8,
                                 -TWO_PI * (float)(tid & 7) / 128.f);
    __syncthreads();
    if (tid < 256) pass8<false, true>(sW, tid << 3, 1, 0.f);
    __syncthreads();
    const float dD = Dp[h];
    const float s4 = 1.0f / (float)NF;
    float2* Kh = KfP + (size_t)h * NF;
    for (int f = tid; f < 2048; f += NTH3) {   // odd bins: (p>>8) odd
        int grp = f >> 8, w = f & 255;
        int p = (2 * grp + 1) * 256 + w;
        int k = ((w & 15) << 8) | (w & 240) | (2 * grp + 1);
        int m = k >> 1;
        float2 v = sW[SW(DR11(m))];
        Kh[p] = make_float2((v.x + dD) * s4, v.y * s4);
    }
    for (int f = tid; f < 2048; f += NTH3) {   // even bins: (p>>8) even
        int grp = f >> 8, w = f & 255;
        int p = grp * 512 + w;                 // k = ((w&15)<<8)|(w&240)|2*grp
        int m = (((w & 15) << 7) | ((w & 240) >> 1)) | grp;   // = k>>1
        float2 v; float sgn;
        if (m <= 1024) { v = sA[m + (m >> 7)]; sgn = 1.f; }
        else { int mm = LSEQ - m; v = sA[mm + (mm >> 7)]; sgn = -1.f; }
        Kh[p] = make_float2((v.x + dD) * s4, sgn * v.y * s4);
    }
}

// FFT convolution: TWO sequences (same hp, b = 2*bb and 2*bb+1) per
// 512-thread block. Each 4-wave half owns one 4096-pt spectrum in its own
// 32-KB LDS region; barriers are shared. Kf row-pair (64 KB) is read once
// per block; the 4 same-hp blocks sit on one XCD (idx%8 = hp&7) so Kf is
// fetched ~once per XCD. Round-3 proven 60-us structure: every phase
// self-contained (no registers live across barriers).
__global__ __launch_bounds__(NTH2, 4) void k_conv(
    float2* __restrict__ W, const float2* __restrict__ Kf)
{
    __shared__ float2 s[2 * NF];
    const int idx = blockIdx.x;
    const int hp = ((idx >> 5) << 3) | (idx & 7);
    const int bb = (idx >> 3) & 3;
    const int half = threadIdx.x >> 8;
    const int t = threadIdx.x & 255;
    const int b = bb * 2 + half;
    float2* sh = s + (half << 12);
    float4* w4 = (float4*)(W + (((size_t)hp * NB + b) << 11));
    for (int i = t; i < 1024; i += 256) {
        float4 v = w4[i];
        sh[SW(2*i)]   = make_float2(v.x, v.y);
        sh[SW(2*i+1)] = make_float2(v.z, v.w);
    }
    __syncthreads();
    // forward DIF 4096 = 16*16*16 (pass 1 exploits zero top half)
    pass16_z(sh, t, 256, -TWO_PI * (float)t / 4096.f);
    __syncthreads();
    pass16<false>(sh, ((t >> 4) << 8) | (t & 15), 16,
                  -TWO_PI * (float)(t & 15) / 256.f);
    __syncthreads();
    pass16<false, true>(sh, t << 4, 1, 0.f);
    __syncthreads();
    // pointwise in permuted domain (pair-ownership: p <= pp, write both)
    const float2* K0 = Kf + (size_t)(2 * hp) * NF;
    const float2* K1 = K0 + NF;
    for (int p = t; p < NF; p += 256) {
        int k  = ((p & 15) << 8) | (p & 240) | (p >> 8);       // bin at pos p
        int kc = (NF - k) & (NF - 1);
        int pp = ((kc & 15) << 8) | (kc & 240) | (kc >> 8);    // conj bin pos
        if (p > pp) continue;
        if (p == pp) {   // self-conjugate bins (k = 0, 2048)
            float2 X = sh[SW(p)];
            float2 g0 = K0[p], g1 = K1[p];
            sh[SW(p)] = make_float2(X.x*g0.x - X.y*g1.y, X.x*g0.y + X.y*g1.x);
        } else {
            float2 Xa = sh[SW(p)], Xb = sh[SW(pp)];
            float2 U0 = make_float2(0.5f*(Xa.x + Xb.x), 0.5f*(Xa.y - Xb.y));
            float2 df = make_float2(Xa.x - Xb.x, Xa.y + Xb.y);
            float2 U1 = make_float2(0.5f*df.y, -0.5f*df.x);
            float2 A0 = K0[p], A1 = K1[p], B0 = K0[pp], B1 = K1[pp];
            float2 y0 = cmul(U0, A0), y1 = cmul(U1, A1);
            sh[SW(p)] = make_float2(y0.x - y1.y, y0.y + y1.x);
            float2 U0c = make_float2(U0.x, -U0.y);
            float2 U1c = make_float2(U1.x, -U1.y);
            float2 z0 = cmul(U0c, B0), z1 = cmul(U1c, B1);
            sh[SW(pp)] = make_float2(z0.x - z1.y, z0.y + z1.x);
        }
    }
    __syncthreads();
    // inverse DIT 4096 (last pass writes only t<2048)
    pass16<true, true>(sh, t << 4, 1, 0.f);
    __syncthreads();
    pass16<true>(sh, ((t >> 4) << 8) | (t & 15), 16,
                 TWO_PI * (float)(t & 15) / 256.f);
    __syncthreads();
    pass16_li(sh, t, 256, TWO_PI * (float)t / 4096.f);
    __syncthreads();
    for (int i = t; i < 1024; i += 256) {
        float2 a = sh[SW(2*i)], c = sh[SW(2*i+1)];
        w4[i] = make_float4(a.x, a.y, c.x, c.y);
    }
}

extern "C" void kernel_launch(void* const* d_in, const int* in_sizes, int n_in,
                              void* d_out, int out_size, void* d_ws, size_t ws_size,
                              hipStream_t stream) {
    const float* u   = (const float*)d_in[0];
    const float* Lre = (const float*)d_in[1];
    const float* Lim = (const float*)d_in[2];
    const float* P   = (const float*)d_in[3];
    const float* B   = (const float*)d_in[4];
    const float* C   = (const float*)d_in[5];
    const float* D   = (const float*)d_in[6];
    const float* ls  = (const float*)d_in[7];

    float2* KfP = (float2*)d_ws;                                   // 16.8 MB
    float2* W   = (float2*)((char*)d_ws +
                            (size_t)NH * NF * sizeof(float2));     // 33.6 MB

    k_tu    <<<dim3(32, 4, 8), NTH, 0, stream>>>((const float2*)u, W);
    k_ck    <<<NH, NTH3, 0, stream>>>(Lre, Lim, P, B, C, ls, D, KfP);
    k_conv  <<<NPAIR * NB / 2, NTH2, 0, stream>>>(W, KfP);
    k_ty    <<<dim3(32, 4, 8), NTH, 0, stream>>>(W, (float2*)d_out);
}

// Round 11
// 217.930 us; speedup vs baseline: 1.0306x; 1.0306x over previous
//
#include <hip/hip_runtime.h>
#include <math.h>

#define NTH 256
#define NTH2 512
#define LSEQ 2048
#define NF 4096
#define NH 512
#define NS 64
#define NB 8
#define NPAIR 256
#define TWO_PI 6.2831853071795864769f
// XOR swizzle: bijective, modifies only bits 0-3; spreads every FFT pass's
// lane pattern evenly over banks.
#define SW(i) ((i) ^ (((i) >> 4) & 15) ^ (((i) >> 8) & 15))
#define DR11(l) ((((l) & 15) << 7) | ((((l) >> 4) & 15) << 3) | ((l) >> 8))

#define C16_1 0.9238795325112867f
#define C16_2 0.7071067811865476f
#define C16_3 0.3826834323650898f

__device__ __forceinline__ float frcp(float x) {
    return __builtin_amdgcn_rcpf(x);
}

__device__ __forceinline__ float2 cmul(float2 a, float2 b) {
    return make_float2(a.x*b.x - a.y*b.y, a.x*b.y + a.y*b.x);
}
__device__ __forceinline__ float2 cmulw(float2 a, float wr, float wi) {
    return make_float2(a.x*wr - a.y*wi, a.x*wi + a.y*wr);
}

// ---- stages 2..4 of the 16-point DIF DFT (shared tail) ----
template<bool INV>
__device__ __forceinline__ void fft16_tail(float2* y) {
    const float sg = INV ? -1.f : 1.f;
    const float WR[8] = {1.f, C16_1, C16_2, C16_3, 0.f, -C16_3, -C16_2, -C16_1};
    const float WI[8] = {0.f, -C16_3, -C16_2, -C16_1, -1.f, -C16_1, -C16_2, -C16_3};
    #pragma unroll
    for (int h = 0; h < 16; h += 8)
        #pragma unroll
        for (int j = 0; j < 4; ++j) {
            float2 a = y[h+j], b = y[h+j+4];
            float2 d = make_float2(a.x-b.x, a.y-b.y);
            y[h+j] = make_float2(a.x+b.x, a.y+b.y);
            y[h+j+4] = cmulw(d, WR[2*j], sg*WI[2*j]);
        }
    #pragma unroll
    for (int h = 0; h < 16; h += 4)
        #pragma unroll
        for (int j = 0; j < 2; ++j) {
            float2 a = y[h+j], b = y[h+j+2];
            float2 d = make_float2(a.x-b.x, a.y-b.y);
            y[h+j] = make_float2(a.x+b.x, a.y+b.y);
            y[h+j+2] = (j == 0) ? d : make_float2(sg*d.y, -sg*d.x);
        }
    #pragma unroll
    for (int h = 0; h < 16; h += 2) {
        float2 a = y[h], b = y[h+1];
        y[h] = make_float2(a.x+b.x, a.y+b.y);
        y[h+1] = make_float2(a.x-b.x, a.y-b.y);
    }
}

// ---- full 16-point DIF DFT. Output: Y[k] = y[rev4[k]]. ----
template<bool INV>
__device__ __forceinline__ void fft16(float2* y) {
    const float sg = INV ? -1.f : 1.f;
    const float WR[8] = {1.f, C16_1, C16_2, C16_3, 0.f, -C16_3, -C16_2, -C16_1};
    const float WI[8] = {0.f, -C16_3, -C16_2, -C16_1, -1.f, -C16_1, -C16_2, -C16_3};
    #pragma unroll
    for (int j = 0; j < 8; ++j) {
        float2 a = y[j], b = y[j+8];
        float2 d = make_float2(a.x-b.x, a.y-b.y);
        y[j] = make_float2(a.x+b.x, a.y+b.y);
        y[j+8] = cmulw(d, WR[j], sg*WI[j]);
    }
    fft16_tail<INV>(y);
}

// ---- 8-point DIF DFT. Output: Y[k] = y[rev3[k]]. ----
template<bool INV>
__device__ __forceinline__ void fft8(float2* y) {
    const float sg = INV ? -1.f : 1.f;
    const float WR[4] = {1.f, C16_2, 0.f, -C16_2};
    const float WI[4] = {0.f, -C16_2, -1.f, -C16_2};
    #pragma unroll
    for (int j = 0; j < 4; ++j) {
        float2 a = y[j], b = y[j+4];
        float2 d = make_float2(a.x-b.x, a.y-b.y);
        y[j] = make_float2(a.x+b.x, a.y+b.y);
        y[j+4] = cmulw(d, WR[j], sg*WI[j]);
    }
    #pragma unroll
    for (int h = 0; h < 8; h += 4)
        #pragma unroll
        for (int j = 0; j < 2; ++j) {
            float2 a = y[h+j], b = y[h+j+2];
            float2 d = make_float2(a.x-b.x, a.y-b.y);
            y[h+j] = make_float2(a.x+b.x, a.y+b.y);
            y[h+j+2] = (j == 0) ? d : make_float2(sg*d.y, -sg*d.x);
        }
    #pragma unroll
    for (int h = 0; h < 8; h += 2) {
        float2 a = y[h], b = y[h+1];
        y[h] = make_float2(a.x+b.x, a.y+b.y);
        y[h+1] = make_float2(a.x-b.x, a.y-b.y);
    }
}

// Radix-16 pass on swizzled LDS. INV=false: DIF forward (natural->DR).
// INV=true: DIT inverse (DR->natural). NOTW=true: all twiddles are 1.
template<bool INV, bool NOTW = false>
__device__ __forceinline__ void pass16(float2* s, int base, int str, float ang1) {
    const int rev4[16] = {0,8,4,12,2,10,6,14,1,9,5,13,3,11,7,15};
    float2 y[16];
    if (!INV) {
        #pragma unroll
        for (int j = 0; j < 16; ++j) y[j] = s[SW(base + j*str)];
        fft16<false>(y);
        if (NOTW) {
            #pragma unroll
            for (int k = 0; k < 16; ++k) s[SW(base + k*str)] = y[rev4[k]];
        } else {
            float sn, cs;
            __sincosf(ang1, &sn, &cs);
            float2 wb = make_float2(cs, sn);
            float2 w = make_float2(1.f, 0.f);
            s[SW(base)] = y[0];
            #pragma unroll
            for (int k = 1; k < 16; ++k) {
                w = cmul(w, wb);
                s[SW(base + k*str)] = cmul(y[rev4[k]], w);
            }
        }
    } else {
        if (NOTW) {
            #pragma unroll
            for (int k = 0; k < 16; ++k) y[k] = s[SW(base + k*str)];
        } else {
            float sn, cs;
            __sincosf(ang1, &sn, &cs);
            float2 wb = make_float2(cs, sn);
            float2 w = make_float2(1.f, 0.f);
            y[0] = s[SW(base)];
            #pragma unroll
            for (int k = 1; k < 16; ++k) {
                w = cmul(w, wb);
                y[k] = cmul(s[SW(base + k*str)], w);
            }
        }
        fft16<true>(y);
        #pragma unroll
        for (int j = 0; j < 16; ++j) s[SW(base + j*str)] = y[rev4[j]];
    }
}

// Forward radix-16 pass with implicit-zero top half (j>=8 inputs are zero).
__device__ __forceinline__ void pass16_z(float2* s, int base, int str, float ang1) {
    const int rev4[16] = {0,8,4,12,2,10,6,14,1,9,5,13,3,11,7,15};
    const float WR[8] = {1.f, C16_1, C16_2, C16_3, 0.f, -C16_3, -C16_2, -C16_1};
    const float WI[8] = {0.f, -C16_3, -C16_2, -C16_1, -1.f, -C16_1, -C16_2, -C16_3};
    float2 y[16];
    float sn, cs;
    __sincosf(ang1, &sn, &cs);
    float2 wb = make_float2(cs, sn);
    #pragma unroll
    for (int j = 0; j < 8; ++j) y[j] = s[SW(base + j*str)];
    #pragma unroll
    for (int j = 0; j < 8; ++j) y[j+8] = cmulw(y[j], WR[j], WI[j]);
    fft16_tail<false>(y);
    float2 w = make_float2(1.f, 0.f);
    s[SW(base)] = y[0];
    #pragma unroll
    for (int k = 1; k < 16; ++k) {
        w = cmul(w, wb);
        s[SW(base + k*str)] = cmul(y[rev4[k]], w);
    }
}

// Final inverse radix-16 pass: only j<8 outputs (t<2048) are needed.
__device__ __forceinline__ void pass16_li(float2* s, int base, int str, float ang1) {
    const int rev4[16] = {0,8,4,12,2,10,6,14,1,9,5,13,3,11,7,15};
    float2 y[16];
    float sn, cs;
    __sincosf(ang1, &sn, &cs);
    float2 wb = make_float2(cs, sn);
    float2 w = make_float2(1.f, 0.f);
    y[0] = s[SW(base)];
    #pragma unroll
    for (int k = 1; k < 16; ++k) {
        w = cmul(w, wb);
        y[k] = cmul(s[SW(base + k*str)], w);
    }
    fft16<true>(y);
    #pragma unroll
    for (int j = 0; j < 8; ++j) s[SW(base + j*str)] = y[rev4[j]];
}

template<bool INV, bool NOTW = false>
__device__ __forceinline__ void pass8(float2* s, int base, int str, float ang1) {
    const int rev3[8] = {0,4,2,6,1,5,3,7};
    float2 y[8];
    if (!INV) {
        #pragma unroll
        for (int j = 0; j < 8; ++j) y[j] = s[SW(base + j*str)];
        fft8<false>(y);
        if (NOTW) {
            #pragma unroll
            for (int k = 0; k < 8; ++k) s[SW(base + k*str)] = y[rev3[k]];
        } else {
            float sn, cs;
            __sincosf(ang1, &sn, &cs);
            float2 wb = make_float2(cs, sn);
            float2 w = make_float2(1.f, 0.f);
            s[SW(base)] = y[0];
            #pragma unroll
            for (int k = 1; k < 8; ++k) {
                w = cmul(w, wb);
                s[SW(base + k*str)] = cmul(y[rev3[k]], w);
            }
        }
    } else {
        if (NOTW) {
            #pragma unroll
            for (int k = 0; k < 8; ++k) y[k] = s[SW(base + k*str)];
        } else {
            float sn, cs;
            __sincosf(ang1, &sn, &cs);
            float2 wb = make_float2(cs, sn);
            float2 w = make_float2(1.f, 0.f);
            y[0] = s[SW(base)];
            #pragma unroll
            for (int k = 1; k < 8; ++k) {
                w = cmul(w, wb);
                y[k] = cmul(s[SW(base + k*str)], w);
            }
        }
        fft8<true>(y);
        #pragma unroll
        for (int j = 0; j < 8; ++j) s[SW(base + j*str)] = y[rev3[j]];
    }
}

// Transpose u [b][t][hp]f2 -> W [hp][b][t]f2 via 64x64 LDS tiles.
__global__ __launch_bounds__(NTH) void k_tu(
    const float2* __restrict__ u2, float2* __restrict__ W)
{
    __shared__ float2 tile[64][65];
    const int t0 = blockIdx.x * 64, hp0 = blockIdx.y * 64, b = blockIdx.z;
    const int tx = threadIdx.x & 63, ty = threadIdx.x >> 6;
    #pragma unroll
    for (int r = 0; r < 64; r += 4)
        tile[r + ty][tx] = u2[((size_t)b * LSEQ + t0 + r + ty) * NPAIR + hp0 + tx];
    __syncthreads();
    #pragma unroll
    for (int r = 0; r < 64; r += 4)
        W[(((size_t)(hp0 + r + ty) * NB + b) << 11) + t0 + tx] = tile[tx][r + ty];
}

// Transpose W [hp][b][t]f2 -> out [b][t][hp]f2.
__global__ __launch_bounds__(NTH) void k_ty(
    const float2* __restrict__ W, float2* __restrict__ out2)
{
    __shared__ float2 tile[64][65];
    const int t0 = blockIdx.x * 64, hp0 = blockIdx.y * 64, b = blockIdx.z;
    const int tx = threadIdx.x & 63, ty = threadIdx.x >> 6;
    #pragma unroll
    for (int r = 0; r < 64; r += 4)   // tile[hp_local][t_local]
        tile[r + ty][tx] = W[(((size_t)(hp0 + r + ty) * NB + b) << 11) + t0 + tx];
    __syncthreads();
    #pragma unroll
    for (int r = 0; r < 64; r += 4)
        out2[((size_t)b * LSEQ + t0 + r + ty) * NPAIR + hp0 + tx] = tile[tx][r + ty];
}

// MERGED k_cauchy + k_kspec, 256-thread blocks (round-9's proven shape:
// 8 freqs/thread amortizes each state's table read; round-10's 4/thread
// regressed 13%). NEW: mirror pairing is REGISTER-LOCAL -- each thread
// owns 4 base freqs l = tid+256j AND their mirrors 2048-l. The mirror's
// tan is free (tan(pi*(2048-l)/2048) = -tan(pi*l/2048) => g1' = -g1), and
// A[l] = (at[l]+conj(at[2048-l]))/2 combines in registers: the 16-KB LDS
// staging arrays, their 8-strided conflicted writes (most of round-9's
// 781K conflict cycles), and one barrier are all deleted. LDS ~27 KB.
// 64 accumulators, none live across barriers; launch_bounds(256,2).
__global__ __launch_bounds__(NTH, 2) void k_ck(
    const float* __restrict__ Lre, const float* __restrict__ Lim,
    const float* __restrict__ Pm, const float* __restrict__ Bm,
    const float* __restrict__ Cm, const float* __restrict__ logstep,
    const float* __restrict__ Dp, float2* __restrict__ KfP)
{
    __shared__ float2 sW[LSEQ];        // 16 KB
    __shared__ float2 sA[1040];        // 8.3 KB: A[0..1024] at sA[l+(l>>7)]
    __shared__ float4 cA[NS];          // dre, dre^2, lam_im, |P|^2
    __shared__ float4 cB[NS];          // conj(C)B, conj(C)P
    __shared__ float2 cC[NS];          // conj(P)B
    const int h = blockIdx.x;
    const int tid = threadIdx.x;
    if (tid < NS) {
        int i = h * NS + tid;
        float Lxx = fminf(Lre[i], -1e-4f), Lyy = Lim[i];
        float Px = Pm[2*i], Py = Pm[2*i+1];
        float Bx = Bm[2*i], By = Bm[2*i+1];
        float Cx = Cm[2*i], Cy = Cm[2*i+1];
        float dre = -Lxx;
        cA[tid] = make_float4(dre, dre*dre, Lyy, Px*Px + Py*Py);
        cB[tid] = make_float4(Cx*Bx + Cy*By, Cx*By - Cy*Bx,
                              Cx*Px + Cy*Py, Cx*Py - Cy*Px);
        cC[tid] = make_float2(Px*Bx + Py*By, Px*By - Py*Bx);
    }
    __syncthreads();
    const float step = expf(logstep[h]);
    const float a2s = 2.0f / step;
    // base freqs l = tid + 256*j (covers 0..1023); mirrors lm = 2048-l
    float tg[4], g1v[4];
    #pragma unroll
    for (int j = 0; j < 4; ++j) {
        int l = tid + 256 * j;
        float r = (float)l * (1.0f / (float)LSEQ);
        tg[j] = sinpif(r) * frcp(cospif(r));     // tan(pi*l/L); mirror = -tg
        g1v[j] = a2s * tg[j];
    }
    // base accumulators b*, mirror accumulators m*
    float b0[4] = {0,0,0,0}, b1[4] = {0,0,0,0};
    float b2[4] = {0,0,0,0}, b3[4] = {0,0,0,0};
    float b4[4] = {0,0,0,0}, b5[4] = {0,0,0,0};
    float b6[4] = {0,0,0,0}, b7[4] = {0,0,0,0};
    float m0[4] = {0,0,0,0}, m1[4] = {0,0,0,0};
    float m2[4] = {0,0,0,0}, m3[4] = {0,0,0,0};
    float m4[4] = {0,0,0,0}, m5[4] = {0,0,0,0};
    float m6[4] = {0,0,0,0}, m7[4] = {0,0,0,0};
    for (int n = 0; n < NS; ++n) {
        float4 ca = cA[n];
        float4 cb = cB[n];
        float2 cc = cC[n];
        #pragma unroll
        for (int j = 0; j < 4; ++j) {
            {   // base freq: g1 = +g1v[j]
                float di = g1v[j] - ca.z;
                float iv = frcp(fmaf(di, di, ca.y));
                float rx = ca.x * iv, ry = di * iv;  // rec = rx - i*ry
                b0[j] += cb.x*rx + cb.y*ry;  b1[j] += cb.y*rx - cb.x*ry;
                b2[j] += cb.z*rx + cb.w*ry;  b3[j] += cb.w*rx - cb.z*ry;
                b4[j] += cc.x*rx + cc.y*ry;  b5[j] += cc.y*rx - cc.x*ry;
                b6[j] += ca.w*rx;            b7[j] -= ca.w*ry;
            }
            {   // mirror freq: g1 = -g1v[j]
                float di = -g1v[j] - ca.z;
                float iv = frcp(fmaf(di, di, ca.y));
                float rx = ca.x * iv, ry = di * iv;
                m0[j] += cb.x*rx + cb.y*ry;  m1[j] += cb.y*rx - cb.x*ry;
                m2[j] += cb.z*rx + cb.w*ry;  m3[j] += cb.w*rx - cb.z*ry;
                m4[j] += cc.x*rx + cc.y*ry;  m5[j] += cc.y*rx - cc.x*ry;
                m6[j] += ca.w*rx;            m7[j] -= ca.w*ry;
            }
        }
    }
    // finalize both, combine A in registers, scatter to sA/sW
    #pragma unroll
    for (int j = 0; j < 4; ++j) {
        // base: (1 + i*tg) * (k00 - k01*k10/(1+k11))
        float denx = 1.0f + b6[j], deny = b7[j];
        float dinv = frcp(denx*denx + deny*deny);
        float numx = b2[j]*b4[j] - b3[j]*b5[j];
        float numy = b2[j]*b5[j] + b3[j]*b4[j];
        float qx = (numx*denx + numy*deny) * dinv;
        float qy = (numy*denx - numx*deny) * dinv;
        float kx = b0[j] - qx, ky = b1[j] - qy;
        float arx = kx - tg[j]*ky;
        float ary = ky + tg[j]*kx;
        // mirror: same with tg' = -tg[j]
        float denxm = 1.0f + m6[j], denym = m7[j];
        float dinvm = frcp(denxm*denxm + denym*denym);
        float numxm = m2[j]*m4[j] - m3[j]*m5[j];
        float numym = m2[j]*m5[j] + m3[j]*m4[j];
        float qxm = (numxm*denxm + numym*denym) * dinvm;
        float qym = (numym*denxm - numxm*denym) * dinvm;
        float kxm = m0[j] - qxm, kym = m1[j] - qym;
        float arxm = kxm + tg[j]*kym;
        float arym = kym - tg[j]*kxm;
        // A[l] = (at[l] + conj(at[2048-l]))/2
        float2 A = make_float2(0.5f*(arx + arxm), 0.5f*(ary - arym));
        int l = tid + 256 * j;
        sA[l + (l >> 7)] = A;
        sW[SW(DR11(l))] = A;
        if (l > 0) sW[SW(DR11(LSEQ - l))] = make_float2(A.x, -A.y);
    }
    if (tid == 0) {
        // l = 1024: tan -> inf limit, A[1024] = Re((step/2)*sum(conj(C)B))
        float sx = 0.f;
        for (int n = 0; n < NS; ++n) sx += cB[n].x;
        float2 Am = make_float2(0.5f * step * sx, 0.f);
        sA[1024 + (1024 >> 7)] = Am;
        sW[SW(DR11(1024))] = Am;
    }
    __syncthreads();
    // inverse DIT-2048 (DR -> natural time)
    pass8<true, true>(sW, tid << 3, 1, 0.f);
    __syncthreads();
    if (tid < 128) pass16<true>(sW, ((tid >> 3) << 7) | (tid & 7), 8,
                                TWO_PI * (float)(tid & 7) / 128.f);
    __syncthreads();
    if (tid < 128) pass16<true>(sW, tid, 128, TWO_PI * (float)tid / 2048.f);
    __syncthreads();
    // modulate: K[t]/2048 * e^{-2pi i t/4096}
    for (int t = tid; t < LSEQ; t += NTH) {
        float kv = sW[SW(t)].x * (1.0f / (float)LSEQ);
        float sn, cs;
        __sincosf(-TWO_PI * (float)t / (float)NF, &sn, &cs);
        sW[SW(t)] = make_float2(kv * cs, kv * sn);
    }
    __syncthreads();
    // forward DIF-2048 (natural -> DR spectrum)
    if (tid < 128) pass16<false>(sW, tid, 128, -TWO_PI * (float)tid / 2048.f);
    __syncthreads();
    if (tid < 128) pass16<false>(sW, ((tid >> 3) << 7) | (tid & 7), 8,
                                 -TWO_PI * (float)(tid & 7) / 128.f);
    __syncthreads();
    pass8<false, true>(sW, tid << 3, 1, 0.f);
    __syncthreads();
    const float dD = Dp[h];
    const float s4 = 1.0f / (float)NF;
    float2* Kh = KfP + (size_t)h * NF;
    #pragma unroll
    for (int g = 0; g < 8; ++g) {      // positions with (p>>8) odd <=> k odd
        int p = (2*g + 1) * 256 + tid;
        int k = ((p & 15) << 8) | (p & 240) | (p >> 8);
        int m = k >> 1;
        float2 v = sW[SW(DR11(m))];
        Kh[p] = make_float2((v.x + dD) * s4, v.y * s4);
    }
    #pragma unroll
    for (int g = 0; g < 8; ++g) {      // positions with (p>>8) even <=> k even
        int p = g * 512 + tid;         // k = ((tid&15)<<8)|(tid&240)|2g
        int m = (((tid & 15) << 7) | ((tid & 240) >> 1)) | g;   // = k>>1
        float2 v; float sgn;
        if (m <= 1024) { v = sA[m + (m >> 7)]; sgn = 1.f; }
        else { int mm = LSEQ - m; v = sA[mm + (mm >> 7)]; sgn = -1.f; }
        Kh[p] = make_float2((v.x + dD) * s4, sgn * v.y * s4);
    }
}

// FFT convolution: TWO sequences (same hp, b = 2*bb and 2*bb+1) per
// 512-thread block. Each 4-wave half owns one 4096-pt spectrum in its own
// 32-KB LDS region; barriers are shared. Kf row-pair (64 KB) is read once
// per block; the 4 same-hp blocks sit on one XCD (idx%8 = hp&7) so Kf is
// fetched ~once per XCD. Round-3 proven 60-us structure: every phase
// self-contained (no registers live across barriers).
__global__ __launch_bounds__(NTH2, 4) void k_conv(
    float2* __restrict__ W, const float2* __restrict__ Kf)
{
    __shared__ float2 s[2 * NF];
    const int idx = blockIdx.x;
    const int hp = ((idx >> 5) << 3) | (idx & 7);
    const int bb = (idx >> 3) & 3;
    const int half = threadIdx.x >> 8;
    const int t = threadIdx.x & 255;
    const int b = bb * 2 + half;
    float2* sh = s + (half << 12);
    float4* w4 = (float4*)(W + (((size_t)hp * NB + b) << 11));
    for (int i = t; i < 1024; i += 256) {
        float4 v = w4[i];
        sh[SW(2*i)]   = make_float2(v.x, v.y);
        sh[SW(2*i+1)] = make_float2(v.z, v.w);
    }
    __syncthreads();
    // forward DIF 4096 = 16*16*16 (pass 1 exploits zero top half)
    pass16_z(sh, t, 256, -TWO_PI * (float)t / 4096.f);
    __syncthreads();
    pass16<false>(sh, ((t >> 4) << 8) | (t & 15), 16,
                  -TWO_PI * (float)(t & 15) / 256.f);
    __syncthreads();
    pass16<false, true>(sh, t << 4, 1, 0.f);
    __syncthreads();
    // pointwise in permuted domain (pair-ownership: p <= pp, write both)
    const float2* K0 = Kf + (size_t)(2 * hp) * NF;
    const float2* K1 = K0 + NF;
    for (int p = t; p < NF; p += 256) {
        int k  = ((p & 15) << 8) | (p & 240) | (p >> 8);       // bin at pos p
        int kc = (NF - k) & (NF - 1);
        int pp = ((kc & 15) << 8) | (kc & 240) | (kc >> 8);    // conj bin pos
        if (p > pp) continue;
        if (p == pp) {   // self-conjugate bins (k = 0, 2048)
            float2 X = sh[SW(p)];
            float2 g0 = K0[p], g1 = K1[p];
            sh[SW(p)] = make_float2(X.x*g0.x - X.y*g1.y, X.x*g0.y + X.y*g1.x);
        } else {
            float2 Xa = sh[SW(p)], Xb = sh[SW(pp)];
            float2 U0 = make_float2(0.5f*(Xa.x + Xb.x), 0.5f*(Xa.y - Xb.y));
            float2 df = make_float2(Xa.x - Xb.x, Xa.y + Xb.y);
            float2 U1 = make_float2(0.5f*df.y, -0.5f*df.x);
            float2 A0 = K0[p], A1 = K1[p], B0 = K0[pp], B1 = K1[pp];
            float2 y0 = cmul(U0, A0), y1 = cmul(U1, A1);
            sh[SW(p)] = make_float2(y0.x - y1.y, y0.y + y1.x);
            float2 U0c = make_float2(U0.x, -U0.y);
            float2 U1c = make_float2(U1.x, -U1.y);
            float2 z0 = cmul(U0c, B0), z1 = cmul(U1c, B1);
            sh[SW(pp)] = make_float2(z0.x - z1.y, z0.y + z1.x);
        }
    }
    __syncthreads();
    // inverse DIT 4096 (last pass writes only t<2048)
    pass16<true, true>(sh, t << 4, 1, 0.f);
    __syncthreads();
    pass16<true>(sh, ((t >> 4) << 8) | (t & 15), 16,
                 TWO_PI * (float)(t & 15) / 256.f);
    __syncthreads();
    pass16_li(sh, t, 256, TWO_PI * (float)t / 4096.f);
    __syncthreads();
    for (int i = t; i < 1024; i += 256) {
        float2 a = sh[SW(2*i)], c = sh[SW(2*i+1)];
        w4[i] = make_float4(a.x, a.y, c.x, c.y);
    }
}

extern "C" void kernel_launch(void* const* d_in, const int* in_sizes, int n_in,
                              void* d_out, int out_size, void* d_ws, size_t ws_size,
                              hipStream_t stream) {
    const float* u   = (const float*)d_in[0];
    const float* Lre = (const float*)d_in[1];
    const float* Lim = (const float*)d_in[2];
    const float* P   = (const float*)d_in[3];
    const float* B   = (const float*)d_in[4];
    const float* C   = (const float*)d_in[5];
    const float* D   = (const float*)d_in[6];
    const float* ls  = (const float*)d_in[7];

    float2* KfP = (float2*)d_ws;                                   // 16.8 MB
    float2* W   = (float2*)((char*)d_ws +
                            (size_t)NH * NF * sizeof(float2));     // 33.6 MB

    k_tu    <<<dim3(32, 4, 8), NTH, 0, stream>>>((const float2*)u, W);
    k_ck    <<<NH, NTH, 0, stream>>>(Lre, Lim, P, B, C, ls, D, KfP);
    k_conv  <<<NPAIR * NB / 2, NTH2, 0, stream>>>(W, KfP);
    k_ty    <<<dim3(32, 4, 8), NTH, 0, stream>>>(W, (float2*)d_out);
}